// Round 8
// baseline (169.514 us; speedup 1.0000x reference)
//
#include <hip/hip_runtime.h>
#include <hip/hip_bf16.h>
#include <cstddef>
#include <cstdint>

#define Bb 4
#define Tt 1024
#define Dd 1024
#define Hh 16

typedef __bf16 bf16x8 __attribute__((ext_vector_type(8)));
typedef __bf16 bf16x4 __attribute__((ext_vector_type(4)));
typedef float  f32x4  __attribute__((ext_vector_type(4)));

__device__ __forceinline__ void gload16(const void* g, void* l) {
    __builtin_amdgcn_global_load_lds(
        (const __attribute__((address_space(1))) void*)g,
        (__attribute__((address_space(3))) void*)l, 16, 0, 0);
}

#define VMC6() asm volatile("s_waitcnt vmcnt(6)" ::: "memory")
#define VMC4() asm volatile("s_waitcnt vmcnt(4)" ::: "memory")
#define VMC0() asm volatile("s_waitcnt vmcnt(0)" ::: "memory")
#define RAWBAR() asm volatile("s_barrier" ::: "memory")

// ---------------------------------------------------------------------------
// Fused prep: [0,4096) cast x -> bf16; [4096,4864) Wqkv transpose;
// [4864,5120) Wproj transpose.  (bf16x4 transpose stores, R3)
// ---------------------------------------------------------------------------
__global__ __launch_bounds__(256) void prep(const float* __restrict__ x,
                                            const float* __restrict__ Wqkv,
                                            const float* __restrict__ Wproj,
                                            __bf16* __restrict__ xb,
                                            __bf16* __restrict__ wqT,
                                            __bf16* __restrict__ wpT) {
    const int bid = blockIdx.x;
    if (bid < 4096) {  // cast
        int i = bid * 256 + threadIdx.x;
        float4 v = ((const float4*)x)[i];
        bf16x4 o = { (__bf16)v.x, (__bf16)v.y, (__bf16)v.z, (__bf16)v.w };
        ((bf16x4*)xb)[i] = o;
        return;
    }
    __shared__ float ld[64][65];
    const float* in;
    __bf16* out;
    int K, N, k0, n0;
    if (bid < 4096 + 768) {
        int j = bid - 4096;
        in = Wqkv; out = wqT; K = 1024; N = 3072;
        k0 = (j & 15) * 64; n0 = (j >> 4) * 64;
    } else {
        int j = bid - 4096 - 768;
        in = Wproj; out = wpT; K = 1024; N = 1024;
        k0 = (j & 15) * 64; n0 = (j >> 4) * 64;
    }
    #pragma unroll
    for (int i = 0; i < 16; i++) {
        int idx = i * 256 + threadIdx.x;
        int r = idx >> 6, c = idx & 63;
        ld[r][c] = in[(size_t)(k0 + r) * N + n0 + c];
    }
    __syncthreads();
    #pragma unroll
    for (int i = 0; i < 4; i++) {
        int idx = i * 256 + threadIdx.x;      // 0..1023: r = out-row, c4 = col quad
        int r = idx >> 4, c4 = (idx & 15) * 4;
        bf16x4 o = { (__bf16)ld[c4][r], (__bf16)ld[c4 + 1][r],
                     (__bf16)ld[c4 + 2][r], (__bf16)ld[c4 + 3][r] };
        *(bf16x4*)&out[(size_t)(n0 + r) * K + k0 + c4] = o;
    }
}

// ---------------------------------------------------------------------------
// 128x128 MFMA GEMM (QKV), BK=32, TRIPLE-buffered (48 KiB LDS, 3 blocks/CU),
// prefetch depth 2, raw s_barrier + counted vmcnt(4).  (R5 exact — the R7
// frag-prefetch unroll regressed 4 µs by collapsing vmcnt depth to 0.)
// V-block (col0>=2048) Cout stores dead -> only vt transpose emitted.
// Q columns (<1024) pre-scaled by 0.125.
// ---------------------------------------------------------------------------
__global__ __launch_bounds__(256) void gemm_qkv(const __bf16* __restrict__ A,
                                                const __bf16* __restrict__ Bt,
                                                const float* __restrict__ bias,
                                                __bf16* __restrict__ Cout,
                                                __bf16* __restrict__ vt,
                                                int M, int N, int K) {
    __shared__ __align__(16) __bf16 smem[24576];  // 3 x (A 4096 | B 4096) = 48 KiB

    const int tid  = threadIdx.x;
    const int lane = tid & 63;
    const int wave = tid >> 6;
    const int wy = wave >> 1, wx = wave & 1;
    const int l15 = lane & 15, quad = lane >> 4;
    const size_t row0 = (size_t)blockIdx.y * 128;
    const size_t col0 = (size_t)blockIdx.x * 128;

    f32x4 acc[4][4] = {};

    // per-lane staging offsets (constant across tiles)
    const int c0 = tid, c1 = 256 + tid;
    const int r0 = c0 >> 2, s0 = (c0 & 3) ^ ((r0 >> 1) & 3);
    const int r1 = c1 >> 2, s1 = (c1 & 3) ^ ((r1 >> 1) & 3);

#define STAGE(it, buf) do {                                                   \
        const int _k0 = (it) << 5;                                            \
        gload16(&A[(row0 + r0) * K + _k0 + s0 * 8], &(buf)[c0 * 8]);          \
        gload16(&Bt[(col0 + r0) * K + _k0 + s0 * 8], &(buf)[4096 + c0 * 8]);  \
        gload16(&A[(row0 + r1) * K + _k0 + s1 * 8], &(buf)[c1 * 8]);          \
        gload16(&Bt[(col0 + r1) * K + _k0 + s1 * 8], &(buf)[4096 + c1 * 8]);  \
    } while (0)

    __bf16 *b0 = smem, *b1 = smem + 8192, *b2 = smem + 16384;
    STAGE(0, b0);
    STAGE(1, b1);

    const int niter = K >> 5;  // 32
    for (int it = 0; it < niter; it++) {
        if (it + 1 < niter) VMC4(); else VMC0();
        RAWBAR();
        if (it + 2 < niter) STAGE(it + 2, b2);

        bf16x8 af[4], bfr[4];
        #pragma unroll
        for (int i = 0; i < 4; i++) {
            const int r = wy * 64 + i * 16 + l15;
            af[i] = *(const bf16x8*)&b0[r * 32 + ((quad ^ ((r >> 1) & 3)) * 8)];
        }
        #pragma unroll
        for (int j = 0; j < 4; j++) {
            const int r = wx * 64 + j * 16 + l15;
            bfr[j] = *(const bf16x8*)&b0[4096 + r * 32 + ((quad ^ ((r >> 1) & 3)) * 8)];
        }
        #pragma unroll
        for (int i = 0; i < 4; i++)
            #pragma unroll
            for (int j = 0; j < 4; j++)
                acc[i][j] = __builtin_amdgcn_mfma_f32_16x16x32_bf16(af[i], bfr[j], acc[i][j], 0, 0, 0);

        __bf16* tswap = b0; b0 = b1; b1 = b2; b2 = tswap;   // rotate ring
    }
#undef STAGE

    // ---- epilogue: bias+scale -> LDS tile (stride 132) -> coalesced stores ----
    __syncthreads();
    const float scale = (col0 < 1024) ? 0.125f : 1.0f;
    #pragma unroll
    for (int j = 0; j < 4; j++) {
        const int cl = wx * 64 + j * 16 + l15;
        const float bj = bias[col0 + cl];
        #pragma unroll
        for (int i = 0; i < 4; i++) {
            const int rl = wy * 64 + i * 16 + quad * 4;
            #pragma unroll
            for (int r = 0; r < 4; r++)
                smem[(rl + r) * 132 + cl] = (__bf16)((acc[i][j][r] + bj) * scale);
        }
    }
    __syncthreads();
    if (col0 < 2048) {  // Q/K blocks: coalesced qkv stores (V's Cout is dead)
        #pragma unroll
        for (int p = 0; p < 8; p++) {
            const int row = p * 16 + (tid >> 4);
            const int ch  = tid & 15;
            bf16x8 v = *(const bf16x8*)&smem[row * 132 + ch * 8];
            *(bf16x8*)&Cout[(row0 + row) * N + col0 + ch * 8] = v;
        }
    } else {  // V block: write only vt[b][h][d][t] (t = M rows)
        const int bidx = (int)(row0 >> 10);
        const int t0g  = (int)(row0 & 1023);
        const int cl   = tid >> 1;          // tile column 0..127
        const int half = tid & 1;           // t-half 0..1
        const int hd   = (int)(col0 - 2048) + cl;
        const size_t vrow = ((size_t)((bidx * Hh + (hd >> 6)) * 64 + (hd & 63))) * Tt + t0g;
        #pragma unroll
        for (int s = 0; s < 8; s++) {
            const int t = half * 64 + s * 8;
            bf16x8 v;
            #pragma unroll
            for (int u = 0; u < 8; u++) v[u] = smem[(t + u) * 132 + cl];
            *(bf16x8*)&vt[vrow + t] = v;
        }
    }
}

// ---------------------------------------------------------------------------
// 128x64-tile GEMM (proj), BK=64, triple-buffered ring, prefetch depth 2,
// raw s_barrier + counted vmcnt(6).  (R5 exact)
// ---------------------------------------------------------------------------
__device__ __forceinline__ void stage_proj(const __bf16* __restrict__ A,
                                           const __bf16* __restrict__ Bt,
                                           size_t row0, size_t col0, int K, int k0,
                                           __bf16* buf, int tid) {
    #pragma unroll
    for (int i = 0; i < 4; i++) {
        int c = i * 256 + tid;
        int r = c >> 3, seg = (c & 7) ^ (r & 7);
        gload16(&A[(row0 + r) * K + k0 + seg * 8], &buf[c * 8]);
    }
    #pragma unroll
    for (int i = 0; i < 2; i++) {
        int c = i * 256 + tid;
        int r = c >> 3, seg = (c & 7) ^ (r & 7);
        gload16(&Bt[(col0 + r) * K + k0 + seg * 8], &buf[8192 + c * 8]);
    }
}

__global__ __launch_bounds__(256) void gemm_bf16_n64(const __bf16* __restrict__ A,
                                                     const __bf16* __restrict__ Bt,
                                                     const float* __restrict__ bias,
                                                     float* __restrict__ Cout,
                                                     int M, int N, int K) {
    __shared__ __align__(16) __bf16 smem[36864];  // 3 x (A 8192 | B 4096) = 72 KiB
    const int tid  = threadIdx.x;
    const int lane = tid & 63;
    const int wave = tid >> 6;
    const int wy = wave >> 1, wx = wave & 1;
    const int l15 = lane & 15, quad = lane >> 4;
    const size_t row0 = (size_t)blockIdx.y * 128;
    const size_t col0 = (size_t)blockIdx.x * 64;

    f32x4 acc[4][2] = {};

    __bf16 *b0 = smem, *b1 = smem + 12288, *b2 = smem + 24576;
    stage_proj(A, Bt, row0, col0, K, 0, b0, tid);
    stage_proj(A, Bt, row0, col0, K, 64, b1, tid);

    const int niter = K >> 6;  // 16
    for (int it = 0; it < niter; ++it) {
        if (it + 1 < niter) VMC6(); else VMC0();
        RAWBAR();
        if (it + 2 < niter) stage_proj(A, Bt, row0, col0, K, (it + 2) << 6, b2, tid);

        #pragma unroll
        for (int kc = 0; kc < 2; kc++) {
            bf16x8 af[4], bfr[2];
            #pragma unroll
            for (int i = 0; i < 4; i++)
                af[i] = *(const bf16x8*)&b0[(wy * 64 + i * 16 + l15) * 64 +
                                            (((kc * 4 + quad) ^ (l15 & 7)) * 8)];
            #pragma unroll
            for (int j = 0; j < 2; j++)
                bfr[j] = *(const bf16x8*)&b0[8192 + (wx * 32 + j * 16 + l15) * 64 +
                                             (((kc * 4 + quad) ^ (l15 & 7)) * 8)];
            #pragma unroll
            for (int i = 0; i < 4; i++)
                #pragma unroll
                for (int j = 0; j < 2; j++)
                    acc[i][j] = __builtin_amdgcn_mfma_f32_16x16x32_bf16(af[i], bfr[j], acc[i][j], 0, 0, 0);
        }

        __bf16* tswap = b0; b0 = b1; b1 = b2; b2 = tswap;   // rotate ring
    }

    #pragma unroll
    for (int j = 0; j < 2; j++) {
        const size_t col = col0 + wx * 32 + j * 16 + l15;
        const float bj = bias[col];
        #pragma unroll
        for (int i = 0; i < 4; i++) {
            const size_t row = row0 + wy * 64 + i * 16 + quad * 4;
            #pragma unroll
            for (int r = 0; r < 4; r++)
                Cout[(row + r) * N + col] = acc[i][j][r] + bj;
        }
    }
}

// ---------------------------------------------------------------------------
// Flash attention (S^T = K @ Q^T).  NEW (R8): QBLK 64 -> 128.  Each staged
// 16 KB K/V tile now feeds 64 MFMA instead of 32; iterations per (b,h) drop
// 136 -> 72 (-47% barriers+DMA); shared ak/av LDS reads per unit work halve.
// Per wave: TWO 16-row q-groups (A: w*32+l15, B: +16), 4 Q frags, 8 Oacc,
// Ps grows to [4][2048] (LDS 48 KiB -> 3 blocks/CU cap; grid gives 2).
// Diagonal: tiles kt >= 2*qt apply tloc <= wq + (2qt-kt)*64 (negative lim
// = fully masked half-tile, accepted waste).  Grid (64, 8), LPT qt = 7-y.
// ---------------------------------------------------------------------------
__global__ __launch_bounds__(256, 2) void attn_mfma(const __bf16* __restrict__ qkv,
                                                    const __bf16* __restrict__ vt,
                                                    const int* __restrict__ mask,
                                                    __bf16* __restrict__ att) {
    __shared__ __align__(16) __bf16 Ks[2][4096];
    __shared__ __align__(16) __bf16 Vs[2][4096];
    __shared__ __align__(16) __bf16 Ps[4][2048];

    const int h  = blockIdx.x & 15;
    const int b  = blockIdx.x >> 4;
    const int qt = 7 - blockIdx.y;  // LPT: longest blocks dispatch first
    const int tid = threadIdx.x, lane = tid & 63, wave = tid >> 6;
    const int l15 = lane & 15, quad = lane >> 4;

    // ---- stage Q (128 rows x 64, swizzled) through Ks[0..1] contiguous ----
    #pragma unroll
    for (int i = 0; i < 4; i++) {
        int c = i * 256 + tid;               // 0..1023 chunks of 8
        int rr = c >> 3, ch = c & 7;
        gload16(&qkv[((size_t)(b * Tt + qt * 128 + rr)) * 3072 + h * 64 + ((ch ^ (rr & 7)) * 8)],
                &Ks[0][c * 8]);
    }

    // mask ballot pass: tile p's 64 bits end up in lane-group (lane&15)==p
    uint32_t mlo = 0, mhi = 0;
    for (int p = 0; p < 16; p++) {
        unsigned long long bal = __ballot(mask[b * Tt + p * 64 + lane] != 0);
        if ((lane & 15) == p) { mlo = (uint32_t)bal; mhi = (uint32_t)(bal >> 32); }
    }

    __syncthreads();
    const __bf16* const Kall = &Ks[0][0];
    const int x7 = l15 & 7;
    bf16x8 qfA0 = *(const bf16x8*)&Kall[(wave * 32 + l15) * 64 + ((quad ^ x7) * 8)];
    bf16x8 qfA1 = *(const bf16x8*)&Kall[(wave * 32 + l15) * 64 + (((4 + quad) ^ x7) * 8)];
    bf16x8 qfB0 = *(const bf16x8*)&Kall[(wave * 32 + 16 + l15) * 64 + ((quad ^ x7) * 8)];
    bf16x8 qfB1 = *(const bf16x8*)&Kall[(wave * 32 + 16 + l15) * 64 + (((4 + quad) ^ x7) * 8)];
    __syncthreads();  // Q frag reads done -> Ks reusable

    #pragma unroll
    for (int i = 0; i < 2; i++) {
        int c = i * 256 + tid;
        int rr = c >> 3, ch = c & 7, sw = ((ch ^ (rr & 7)) * 8);
        gload16(&qkv[((size_t)(b * Tt + rr)) * 3072 + 1024 + h * 64 + sw], &Ks[0][c * 8]);
        gload16(&vt[((size_t)((b * Hh + h) * 64 + rr)) * Tt + sw], &Vs[0][c * 8]);
    }

    f32x4 OA[4] = {}, OB[4] = {};
    float lsA = 0.0f, lsB = 0.0f;
    const int ktmax = 2 * qt + 1;

    for (int kt = 0; kt <= ktmax; kt++) {
        __syncthreads();  // DMA(kt) complete (issued a full compute phase ago)
        const int cur = kt & 1;
        if (kt < ktmax) {
            #pragma unroll
            for (int i = 0; i < 2; i++) {
                int c = i * 256 + tid;
                int rr = c >> 3, ch = c & 7, sw = ((ch ^ (rr & 7)) * 8);
                gload16(&qkv[((size_t)(b * Tt + (kt + 1) * 64 + rr)) * 3072 + 1024 + h * 64 + sw],
                        &Ks[cur ^ 1][c * 8]);
                gload16(&vt[((size_t)((b * Hh + h) * 64 + rr)) * Tt + (kt + 1) * 64 + sw],
                        &Vs[cur ^ 1][c * 8]);
            }
        }

        // mask bits for this tile (uniform readlane, no memory access)
        const uint32_t lo = (uint32_t)__builtin_amdgcn_readlane((int)mlo, kt);
        const uint32_t hi = (uint32_t)__builtin_amdgcn_readlane((int)mhi, kt);
        const bool diag = (kt >= 2 * qt);
        const int dlim = (2 * qt - kt) * 64;    // add wq to get the k limit

        bf16x8 ak[4][2];
        #pragma unroll
        for (int j = 0; j < 4; j++)
            #pragma unroll
            for (int kc = 0; kc < 2; kc++)
                ak[j][kc] = *(const bf16x8*)&Ks[cur][(j * 16 + l15) * 64 +
                                                     (((kc * 4 + quad) ^ x7) * 8)];
        // ---- QK^T + exp, group A (q = wave*32 + l15) ----
        #pragma unroll
        for (int j = 0; j < 4; j++) {
            f32x4 st = {};
            st = __builtin_amdgcn_mfma_f32_16x16x32_bf16(ak[j][0], qfA0, st, 0, 0, 0);
            st = __builtin_amdgcn_mfma_f32_16x16x32_bf16(ak[j][1], qfA1, st, 0, 0, 0);
            const uint32_t fld = (j < 2) ? (lo >> (j * 16)) : (hi >> ((j - 2) * 16));
            const int lim = wave * 32 + l15 + dlim;
            bf16x4 pv;
            #pragma unroll
            for (int r = 0; r < 4; r++) {
                const int tloc = j * 16 + quad * 4 + r;
                bool keep = (fld >> (quad * 4 + r)) & 1;
                if (diag) keep = keep && (tloc <= lim);
                const float pe = keep ? __expf(st[r]) : 0.0f;
                lsA += pe;
                pv[r] = (__bf16)pe;
            }
            *(bf16x4*)&Ps[wave][l15 * 64 + (((j * 4 + quad) ^ (x7 << 1)) * 4)] = pv;
        }
        // ---- QK^T + exp, group B (q = wave*32 + 16 + l15) ----
        #pragma unroll
        for (int j = 0; j < 4; j++) {
            f32x4 st = {};
            st = __builtin_amdgcn_mfma_f32_16x16x32_bf16(ak[j][0], qfB0, st, 0, 0, 0);
            st = __builtin_amdgcn_mfma_f32_16x16x32_bf16(ak[j][1], qfB1, st, 0, 0, 0);
            const uint32_t fld = (j < 2) ? (lo >> (j * 16)) : (hi >> ((j - 2) * 16));
            const int lim = wave * 32 + 16 + l15 + dlim;
            bf16x4 pv;
            #pragma unroll
            for (int r = 0; r < 4; r++) {
                const int tloc = j * 16 + quad * 4 + r;
                bool keep = (fld >> (quad * 4 + r)) & 1;
                if (diag) keep = keep && (tloc <= lim);
                const float pe = keep ? __expf(st[r]) : 0.0f;
                lsB += pe;
                pv[r] = (__bf16)pe;
            }
            *(bf16x4*)&Ps[wave][(16 + l15) * 64 + (((j * 4 + quad) ^ (x7 << 1)) * 4)] = pv;
        }

        // ---- PV for both groups (shared av reads) ----
        bf16x8 av[4][2];
        #pragma unroll
        for (int n = 0; n < 4; n++)
            #pragma unroll
            for (int kc = 0; kc < 2; kc++)
                av[n][kc] = *(const bf16x8*)&Vs[cur][(n * 16 + l15) * 64 +
                                                     (((kc * 4 + quad) ^ x7) * 8)];
        bf16x8 pA0 = *(const bf16x8*)&Ps[wave][l15 * 64 + (((2 * quad) ^ (x7 << 1)) * 4)];
        bf16x8 pA1 = *(const bf16x8*)&Ps[wave][l15 * 64 + (((2 * (4 + quad)) ^ (x7 << 1)) * 4)];
        bf16x8 pB0 = *(const bf16x8*)&Ps[wave][(16 + l15) * 64 + (((2 * quad) ^ (x7 << 1)) * 4)];
        bf16x8 pB1 = *(const bf16x8*)&Ps[wave][(16 + l15) * 64 + (((2 * (4 + quad)) ^ (x7 << 1)) * 4)];
        #pragma unroll
        for (int n = 0; n < 4; n++) {
            OA[n] = __builtin_amdgcn_mfma_f32_16x16x32_bf16(av[n][0], pA0, OA[n], 0, 0, 0);
            OA[n] = __builtin_amdgcn_mfma_f32_16x16x32_bf16(av[n][1], pA1, OA[n], 0, 0, 0);
            OB[n] = __builtin_amdgcn_mfma_f32_16x16x32_bf16(av[n][0], pB0, OB[n], 0, 0, 0);
            OB[n] = __builtin_amdgcn_mfma_f32_16x16x32_bf16(av[n][1], pB1, OB[n], 0, 0, 0);
        }
    }

    float ltA = lsA;
    ltA += __shfl_xor(ltA, 16);
    ltA += __shfl_xor(ltA, 32);
    float ltB = lsB;
    ltB += __shfl_xor(ltB, 16);
    ltB += __shfl_xor(ltB, 32);
    const float invA = 1.0f / ltA;
    const float invB = 1.0f / ltB;
    const int qA = qt * 128 + wave * 32 + l15;
    #pragma unroll
    for (int n = 0; n < 4; n++) {
        bf16x4 oa, ob;
        #pragma unroll
        for (int r = 0; r < 4; r++) { oa[r] = (__bf16)(OA[n][r] * invA); ob[r] = (__bf16)(OB[n][r] * invB); }
        *(bf16x4*)&att[((size_t)(b * Tt + qA)) * Dd + h * 64 + n * 16 + quad * 4] = oa;
        *(bf16x4*)&att[((size_t)(b * Tt + qA + 16)) * Dd + h * 64 + n * 16 + quad * 4] = ob;
    }
}

// ---------------------------------------------------------------------------
extern "C" void kernel_launch(void* const* d_in, const int* in_sizes, int n_in,
                              void* d_out, int out_size, void* d_ws, size_t ws_size,
                              hipStream_t stream) {
    const float* x     = (const float*)d_in[0];
    const float* Wqkv  = (const float*)d_in[1];
    const float* bqkv  = (const float*)d_in[2];
    const float* Wproj = (const float*)d_in[3];
    const float* bproj = (const float*)d_in[4];
    const int*   mask  = (const int*)d_in[5];
    float* out = (float*)d_out;

    __bf16* xb  = (__bf16*)d_ws;                         // 4096*1024
    __bf16* wqT = xb  + (size_t)4096 * 1024;             // 3072*1024
    __bf16* wpT = wqT + (size_t)3072 * 1024;             // 1024*1024
    __bf16* qkv = wpT + (size_t)1024 * 1024;             // 4096*3072
    __bf16* vt  = qkv + (size_t)4096 * 3072;             // 4*16*64*1024
    __bf16* att = vt  + (size_t)4 * 16 * 64 * 1024;      // 4096*1024

    prep<<<4096 + 768 + 256, 256, 0, stream>>>(x, Wqkv, Wproj, xb, wqT, wpT);

    gemm_qkv<<<dim3(24, 32), 256, 0, stream>>>(xb, wqT, bqkv, qkv, vt, 4096, 3072, 1024);

    attn_mfma<<<dim3(64, 8), 256, 0, stream>>>(qkv, vt, mask, att);

    gemm_bf16_n64<<<dim3(16, 32), 256, 0, stream>>>(att, wpT, bproj, out, 4096, 1024, 1024);
}

// Round 10
// 161.334 us; speedup vs baseline: 1.0507x; 1.0507x over previous
//
#include <hip/hip_runtime.h>
#include <hip/hip_bf16.h>
#include <cstddef>
#include <cstdint>

#define Bb 4
#define Tt 1024
#define Dd 1024
#define Hh 16

typedef __bf16 bf16x8 __attribute__((ext_vector_type(8)));
typedef __bf16 bf16x4 __attribute__((ext_vector_type(4)));
typedef float  f32x4  __attribute__((ext_vector_type(4)));

__device__ __forceinline__ void gload16(const void* g, void* l) {
    __builtin_amdgcn_global_load_lds(
        (const __attribute__((address_space(1))) void*)g,
        (__attribute__((address_space(3))) void*)l, 16, 0, 0);
}

#define VMC6() asm volatile("s_waitcnt vmcnt(6)" ::: "memory")
#define VMC4() asm volatile("s_waitcnt vmcnt(4)" ::: "memory")
#define VMC0() asm volatile("s_waitcnt vmcnt(0)" ::: "memory")
#define RAWBAR() asm volatile("s_barrier" ::: "memory")

// ---------------------------------------------------------------------------
// Fused prep: [0,4096) cast x -> bf16; [4096,4864) Wqkv transpose;
// [4864,5120) Wproj transpose.  (bf16x4 transpose stores, R3)
// ---------------------------------------------------------------------------
__global__ __launch_bounds__(256) void prep(const float* __restrict__ x,
                                            const float* __restrict__ Wqkv,
                                            const float* __restrict__ Wproj,
                                            __bf16* __restrict__ xb,
                                            __bf16* __restrict__ wqT,
                                            __bf16* __restrict__ wpT) {
    const int bid = blockIdx.x;
    if (bid < 4096) {  // cast
        int i = bid * 256 + threadIdx.x;
        float4 v = ((const float4*)x)[i];
        bf16x4 o = { (__bf16)v.x, (__bf16)v.y, (__bf16)v.z, (__bf16)v.w };
        ((bf16x4*)xb)[i] = o;
        return;
    }
    __shared__ float ld[64][65];
    const float* in;
    __bf16* out;
    int K, N, k0, n0;
    if (bid < 4096 + 768) {
        int j = bid - 4096;
        in = Wqkv; out = wqT; K = 1024; N = 3072;
        k0 = (j & 15) * 64; n0 = (j >> 4) * 64;
    } else {
        int j = bid - 4096 - 768;
        in = Wproj; out = wpT; K = 1024; N = 1024;
        k0 = (j & 15) * 64; n0 = (j >> 4) * 64;
    }
    #pragma unroll
    for (int i = 0; i < 16; i++) {
        int idx = i * 256 + threadIdx.x;
        int r = idx >> 6, c = idx & 63;
        ld[r][c] = in[(size_t)(k0 + r) * N + n0 + c];
    }
    __syncthreads();
    #pragma unroll
    for (int i = 0; i < 4; i++) {
        int idx = i * 256 + threadIdx.x;      // 0..1023: r = out-row, c4 = col quad
        int r = idx >> 4, c4 = (idx & 15) * 4;
        bf16x4 o = { (__bf16)ld[c4][r], (__bf16)ld[c4 + 1][r],
                     (__bf16)ld[c4 + 2][r], (__bf16)ld[c4 + 3][r] };
        *(bf16x4*)&out[(size_t)(n0 + r) * K + k0 + c4] = o;
    }
}

// ---------------------------------------------------------------------------
// 128x128 MFMA GEMM (QKV), BK=32, TRIPLE-buffered (48 KiB LDS, 3 blocks/CU),
// prefetch depth 2, raw s_barrier + counted vmcnt(4).  (R5 exact)
// V-block (col0>=2048) Cout stores dead -> only vt transpose emitted.
// Q columns (<1024) pre-scaled by 0.125 * log2(e) (R9: softmax base change —
// attn then uses raw v_exp_f32 (exp2) with no per-element multiply).
// ---------------------------------------------------------------------------
__global__ __launch_bounds__(256) void gemm_qkv(const __bf16* __restrict__ A,
                                                const __bf16* __restrict__ Bt,
                                                const float* __restrict__ bias,
                                                __bf16* __restrict__ Cout,
                                                __bf16* __restrict__ vt,
                                                int M, int N, int K) {
    __shared__ __align__(16) __bf16 smem[24576];  // 3 x (A 4096 | B 4096) = 48 KiB

    const int tid  = threadIdx.x;
    const int lane = tid & 63;
    const int wave = tid >> 6;
    const int wy = wave >> 1, wx = wave & 1;
    const int l15 = lane & 15, quad = lane >> 4;
    const size_t row0 = (size_t)blockIdx.y * 128;
    const size_t col0 = (size_t)blockIdx.x * 128;

    f32x4 acc[4][4] = {};

    // per-lane staging offsets (constant across tiles)
    const int c0 = tid, c1 = 256 + tid;
    const int r0 = c0 >> 2, s0 = (c0 & 3) ^ ((r0 >> 1) & 3);
    const int r1 = c1 >> 2, s1 = (c1 & 3) ^ ((r1 >> 1) & 3);

#define STAGE(it, buf) do {                                                   \
        const int _k0 = (it) << 5;                                            \
        gload16(&A[(row0 + r0) * K + _k0 + s0 * 8], &(buf)[c0 * 8]);          \
        gload16(&Bt[(col0 + r0) * K + _k0 + s0 * 8], &(buf)[4096 + c0 * 8]);  \
        gload16(&A[(row0 + r1) * K + _k0 + s1 * 8], &(buf)[c1 * 8]);          \
        gload16(&Bt[(col0 + r1) * K + _k0 + s1 * 8], &(buf)[4096 + c1 * 8]);  \
    } while (0)

    __bf16 *b0 = smem, *b1 = smem + 8192, *b2 = smem + 16384;
    STAGE(0, b0);
    STAGE(1, b1);

    const int niter = K >> 5;  // 32
    for (int it = 0; it < niter; it++) {
        if (it + 1 < niter) VMC4(); else VMC0();
        RAWBAR();
        if (it + 2 < niter) STAGE(it + 2, b2);

        bf16x8 af[4], bfr[4];
        #pragma unroll
        for (int i = 0; i < 4; i++) {
            const int r = wy * 64 + i * 16 + l15;
            af[i] = *(const bf16x8*)&b0[r * 32 + ((quad ^ ((r >> 1) & 3)) * 8)];
        }
        #pragma unroll
        for (int j = 0; j < 4; j++) {
            const int r = wx * 64 + j * 16 + l15;
            bfr[j] = *(const bf16x8*)&b0[4096 + r * 32 + ((quad ^ ((r >> 1) & 3)) * 8)];
        }
        #pragma unroll
        for (int i = 0; i < 4; i++)
            #pragma unroll
            for (int j = 0; j < 4; j++)
                acc[i][j] = __builtin_amdgcn_mfma_f32_16x16x32_bf16(af[i], bfr[j], acc[i][j], 0, 0, 0);

        __bf16* tswap = b0; b0 = b1; b1 = b2; b2 = tswap;   // rotate ring
    }
#undef STAGE

    // ---- epilogue: bias+scale -> LDS tile (stride 132) -> coalesced stores ----
    __syncthreads();
    // Q scale folds 1/sqrt(64) AND log2(e): softmax computed as exp2.
    const float scale = (col0 < 1024) ? 0.18033688011112042f : 1.0f;
    #pragma unroll
    for (int j = 0; j < 4; j++) {
        const int cl = wx * 64 + j * 16 + l15;
        const float bj = bias[col0 + cl];
        #pragma unroll
        for (int i = 0; i < 4; i++) {
            const int rl = wy * 64 + i * 16 + quad * 4;
            #pragma unroll
            for (int r = 0; r < 4; r++)
                smem[(rl + r) * 132 + cl] = (__bf16)((acc[i][j][r] + bj) * scale);
        }
    }
    __syncthreads();
    if (col0 < 2048) {  // Q/K blocks: coalesced qkv stores (V's Cout is dead)
        #pragma unroll
        for (int p = 0; p < 8; p++) {
            const int row = p * 16 + (tid >> 4);
            const int ch  = tid & 15;
            bf16x8 v = *(const bf16x8*)&smem[row * 132 + ch * 8];
            *(bf16x8*)&Cout[(row0 + row) * N + col0 + ch * 8] = v;
        }
    } else {  // V block: write only vt[b][h][d][t] (t = M rows)
        const int bidx = (int)(row0 >> 10);
        const int t0g  = (int)(row0 & 1023);
        const int cl   = tid >> 1;          // tile column 0..127
        const int half = tid & 1;           // t-half 0..1
        const int hd   = (int)(col0 - 2048) + cl;
        const size_t vrow = ((size_t)((bidx * Hh + (hd >> 6)) * 64 + (hd & 63))) * Tt + t0g;
        #pragma unroll
        for (int s = 0; s < 8; s++) {
            const int t = half * 64 + s * 8;
            bf16x8 v;
            #pragma unroll
            for (int u = 0; u < 8; u++) v[u] = smem[(t + u) * 132 + cl];
            *(bf16x8*)&vt[vrow + t] = v;
        }
    }
}

// ---------------------------------------------------------------------------
// 128x64-tile GEMM (proj), BK=64, triple-buffered ring, prefetch depth 2,
// raw s_barrier + counted vmcnt(6).  (R5 exact)
// ---------------------------------------------------------------------------
__device__ __forceinline__ void stage_proj(const __bf16* __restrict__ A,
                                           const __bf16* __restrict__ Bt,
                                           size_t row0, size_t col0, int K, int k0,
                                           __bf16* buf, int tid) {
    #pragma unroll
    for (int i = 0; i < 4; i++) {
        int c = i * 256 + tid;
        int r = c >> 3, seg = (c & 7) ^ (r & 7);
        gload16(&A[(row0 + r) * K + k0 + seg * 8], &buf[c * 8]);
    }
    #pragma unroll
    for (int i = 0; i < 2; i++) {
        int c = i * 256 + tid;
        int r = c >> 3, seg = (c & 7) ^ (r & 7);
        gload16(&Bt[(col0 + r) * K + k0 + seg * 8], &buf[8192 + c * 8]);
    }
}

__global__ __launch_bounds__(256) void gemm_bf16_n64(const __bf16* __restrict__ A,
                                                     const __bf16* __restrict__ Bt,
                                                     const float* __restrict__ bias,
                                                     float* __restrict__ Cout,
                                                     int M, int N, int K) {
    __shared__ __align__(16) __bf16 smem[36864];  // 3 x (A 8192 | B 4096) = 72 KiB
    const int tid  = threadIdx.x;
    const int lane = tid & 63;
    const int wave = tid >> 6;
    const int wy = wave >> 1, wx = wave & 1;
    const int l15 = lane & 15, quad = lane >> 4;
    const size_t row0 = (size_t)blockIdx.y * 128;
    const size_t col0 = (size_t)blockIdx.x * 64;

    f32x4 acc[4][2] = {};

    __bf16 *b0 = smem, *b1 = smem + 12288, *b2 = smem + 24576;
    stage_proj(A, Bt, row0, col0, K, 0, b0, tid);
    stage_proj(A, Bt, row0, col0, K, 64, b1, tid);

    const int niter = K >> 6;  // 16
    for (int it = 0; it < niter; ++it) {
        if (it + 1 < niter) VMC6(); else VMC0();
        RAWBAR();
        if (it + 2 < niter) stage_proj(A, Bt, row0, col0, K, (it + 2) << 6, b2, tid);

        #pragma unroll
        for (int kc = 0; kc < 2; kc++) {
            bf16x8 af[4], bfr[2];
            #pragma unroll
            for (int i = 0; i < 4; i++)
                af[i] = *(const bf16x8*)&b0[(wy * 64 + i * 16 + l15) * 64 +
                                            (((kc * 4 + quad) ^ (l15 & 7)) * 8)];
            #pragma unroll
            for (int j = 0; j < 2; j++)
                bfr[j] = *(const bf16x8*)&b0[8192 + (wx * 32 + j * 16 + l15) * 64 +
                                             (((kc * 4 + quad) ^ (l15 & 7)) * 8)];
            #pragma unroll
            for (int i = 0; i < 4; i++)
                #pragma unroll
                for (int j = 0; j < 2; j++)
                    acc[i][j] = __builtin_amdgcn_mfma_f32_16x16x32_bf16(af[i], bfr[j], acc[i][j], 0, 0, 0);
        }

        __bf16* tswap = b0; b0 = b1; b1 = b2; b2 = tswap;   // rotate ring
    }

    #pragma unroll
    for (int j = 0; j < 2; j++) {
        const size_t col = col0 + wx * 32 + j * 16 + l15;
        const float bj = bias[col];
        #pragma unroll
        for (int i = 0; i < 4; i++) {
            const size_t row = row0 + wy * 64 + i * 16 + quad * 4;
            #pragma unroll
            for (int r = 0; r < 4; r++)
                Cout[(row + r) * N + col] = acc[i][j][r] + bj;
        }
    }
}

// ---------------------------------------------------------------------------
// Flash attention (S^T = K @ Q^T).  R9: R5 QBLK=64 form (QBLK=128 halved
// occupancy 4->2 blocks/CU and regressed; kernel is latency-bound on its
// serial tile chain and lives off cross-block TLP).  Only change vs R5:
// exp -> exp2 (log2e folded into Q pre-scale upstream), removing one VALU
// multiply per score element.
// ---------------------------------------------------------------------------
__global__ __launch_bounds__(256, 4) void attn_mfma(const __bf16* __restrict__ qkv,
                                                    const __bf16* __restrict__ vt,
                                                    const int* __restrict__ mask,
                                                    __bf16* __restrict__ att) {
    __shared__ __align__(16) __bf16 Ks[2][4096];
    __shared__ __align__(16) __bf16 Vs[2][4096];
    __shared__ __align__(16) __bf16 Ps[4][1024];

    const int h  = blockIdx.x & 15;
    const int b  = blockIdx.x >> 4;
    const int qt = 15 - blockIdx.y;  // LPT: longest blocks dispatch first
    const int tid = threadIdx.x, lane = tid & 63, wave = tid >> 6;
    const int l15 = lane & 15, quad = lane >> 4;

    // stage Q (swizzled) through Ks[0]
    #pragma unroll
    for (int i = 0; i < 2; i++) {
        int c = i * 256 + tid;
        int rr = c >> 3, ch = c & 7;
        gload16(&qkv[((size_t)(b * Tt + qt * 64 + rr)) * 3072 + h * 64 + ((ch ^ (rr & 7)) * 8)],
                &Ks[0][c * 8]);
    }

    // mask ballot pass: tile p's 64 bits end up in lane-group (lane&15)==p
    uint32_t mlo = 0, mhi = 0;
    for (int p = 0; p < 16; p++) {
        unsigned long long bal = __ballot(mask[b * Tt + p * 64 + lane] != 0);
        if ((lane & 15) == p) { mlo = (uint32_t)bal; mhi = (uint32_t)(bal >> 32); }
    }

    __syncthreads();
    bf16x8 qf0 = *(const bf16x8*)&Ks[0][(wave * 16 + l15) * 64 + ((quad ^ (l15 & 7)) * 8)];
    bf16x8 qf1 = *(const bf16x8*)&Ks[0][(wave * 16 + l15) * 64 + (((4 + quad) ^ (l15 & 7)) * 8)];
    __syncthreads();  // Q frag reads done -> Ks[0] reusable

    #pragma unroll
    for (int i = 0; i < 2; i++) {
        int c = i * 256 + tid;
        int rr = c >> 3, ch = c & 7, sw = ((ch ^ (rr & 7)) * 8);
        gload16(&qkv[((size_t)(b * Tt + rr)) * 3072 + 1024 + h * 64 + sw], &Ks[0][c * 8]);
        gload16(&vt[((size_t)((b * Hh + h) * 64 + rr)) * Tt + sw], &Vs[0][c * 8]);
    }

    f32x4 Oacc[4] = {};
    float lsum = 0.0f;

    for (int kt = 0; kt <= qt; kt++) {
        __syncthreads();  // DMA(kt) complete (issued a full compute phase ago)
        const int cur = kt & 1;
        if (kt < qt) {
            #pragma unroll
            for (int i = 0; i < 2; i++) {
                int c = i * 256 + tid;
                int rr = c >> 3, ch = c & 7, sw = ((ch ^ (rr & 7)) * 8);
                gload16(&qkv[((size_t)(b * Tt + (kt + 1) * 64 + rr)) * 3072 + 1024 + h * 64 + sw],
                        &Ks[cur ^ 1][c * 8]);
                gload16(&vt[((size_t)((b * Hh + h) * 64 + rr)) * Tt + (kt + 1) * 64 + sw],
                        &Vs[cur ^ 1][c * 8]);
            }
        }

        // mask bits for this tile (uniform readlane, no memory access)
        const uint32_t lo = (uint32_t)__builtin_amdgcn_readlane((int)mlo, kt);
        const uint32_t hi = (uint32_t)__builtin_amdgcn_readlane((int)mhi, kt);

        bf16x8 ak[4][2];
        #pragma unroll
        for (int j = 0; j < 4; j++)
            #pragma unroll
            for (int kc = 0; kc < 2; kc++)
                ak[j][kc] = *(const bf16x8*)&Ks[cur][(j * 16 + l15) * 64 +
                                                     (((kc * 4 + quad) ^ (l15 & 7)) * 8)];
        #pragma unroll
        for (int j = 0; j < 4; j++) {
            f32x4 st = {};
            st = __builtin_amdgcn_mfma_f32_16x16x32_bf16(ak[j][0], qf0, st, 0, 0, 0);
            st = __builtin_amdgcn_mfma_f32_16x16x32_bf16(ak[j][1], qf1, st, 0, 0, 0);
            const uint32_t fld = (j < 2) ? (lo >> (j * 16)) : (hi >> ((j - 2) * 16));
            bf16x4 pv;
            #pragma unroll
            for (int r = 0; r < 4; r++) {
                const int tloc = j * 16 + quad * 4 + r;
                bool keep = (fld >> (quad * 4 + r)) & 1;
                if (kt == qt) keep = keep && (tloc <= wave * 16 + l15);
                const float pe = keep ? exp2f(st[r]) : 0.0f;   // base-2: scale folded upstream
                lsum += pe;
                pv[r] = (__bf16)pe;
            }
            *(bf16x4*)&Ps[wave][l15 * 64 + (((j * 4 + quad) ^ ((l15 & 7) << 1)) * 4)] = pv;
        }

        bf16x8 av[4][2];
        #pragma unroll
        for (int n = 0; n < 4; n++)
            #pragma unroll
            for (int kc = 0; kc < 2; kc++)
                av[n][kc] = *(const bf16x8*)&Vs[cur][(n * 16 + l15) * 64 +
                                                     (((kc * 4 + quad) ^ (l15 & 7)) * 8)];
        bf16x8 p0 = *(const bf16x8*)&Ps[wave][l15 * 64 + (((2 * quad) ^ ((l15 & 7) << 1)) * 4)];
        bf16x8 p1 = *(const bf16x8*)&Ps[wave][l15 * 64 + (((2 * (4 + quad)) ^ ((l15 & 7) << 1)) * 4)];
        #pragma unroll
        for (int n = 0; n < 4; n++) {
            Oacc[n] = __builtin_amdgcn_mfma_f32_16x16x32_bf16(av[n][0], p0, Oacc[n], 0, 0, 0);
            Oacc[n] = __builtin_amdgcn_mfma_f32_16x16x32_bf16(av[n][1], p1, Oacc[n], 0, 0, 0);
        }
    }

    float lt = lsum;
    lt += __shfl_xor(lt, 16);
    lt += __shfl_xor(lt, 32);
    const float inv = 1.0f / lt;
    const int q = qt * 64 + wave * 16 + l15;
    #pragma unroll
    for (int n = 0; n < 4; n++) {
        bf16x4 o;
        #pragma unroll
        for (int r = 0; r < 4; r++) o[r] = (__bf16)(Oacc[n][r] * inv);
        *(bf16x4*)&att[((size_t)(b * Tt + q)) * Dd + h * 64 + n * 16 + quad * 4] = o;
    }
}

// ---------------------------------------------------------------------------
extern "C" void kernel_launch(void* const* d_in, const int* in_sizes, int n_in,
                              void* d_out, int out_size, void* d_ws, size_t ws_size,
                              hipStream_t stream) {
    const float* x     = (const float*)d_in[0];
    const float* Wqkv  = (const float*)d_in[1];
    const float* bqkv  = (const float*)d_in[2];
    const float* Wproj = (const float*)d_in[3];
    const float* bproj = (const float*)d_in[4];
    const int*   mask  = (const int*)d_in[5];
    float* out = (float*)d_out;

    __bf16* xb  = (__bf16*)d_ws;                         // 4096*1024
    __bf16* wqT = xb  + (size_t)4096 * 1024;             // 3072*1024
    __bf16* wpT = wqT + (size_t)3072 * 1024;             // 1024*1024
    __bf16* qkv = wpT + (size_t)1024 * 1024;             // 4096*3072
    __bf16* vt  = qkv + (size_t)4096 * 3072;             // 4*16*64*1024
    __bf16* att = vt  + (size_t)4 * 16 * 64 * 1024;      // 4096*1024

    prep<<<4096 + 768 + 256, 256, 0, stream>>>(x, Wqkv, Wproj, xb, wqT, wpT);

    gemm_qkv<<<dim3(24, 32), 256, 0, stream>>>(xb, wqT, bqkv, qkv, vt, 4096, 3072, 1024);

    attn_mfma<<<dim3(64, 16), 256, 0, stream>>>(qkv, vt, mask, att);

    gemm_bf16_n64<<<dim3(16, 32), 256, 0, stream>>>(att, wpT, bproj, out, 4096, 1024, 1024);
}